// Round 1
// baseline (1716.052 us; speedup 1.0000x reference)
//
#include <hip/hip_runtime.h>

// Problem constants (from reference)
constexpr int CB   = 128;   // batch
constexpr int CC   = 12;    // channels
constexpr int CL   = 2048;  // length
constexpr int CK   = 8;     // kernels per group
constexpr int CG   = 32;    // _G = G/2
constexpr int CNCP = 6;     // channels summed per group
constexpr int CND  = 8;     // dilations
constexpr int HALO = 512;   // max tap reach = 4*128
constexpr int BUF  = HALO + CL + HALO + 16; // padded LDS row

// ---------------------------------------------------------------------------
// Transpose W [pair][g*8+k][9] -> Wt [pair][g][j*8+k]  (contiguous per (j))
// so the block-uniform weight reads become wide scalar loads.
// ---------------------------------------------------------------------------
__global__ void transposeW(const float* __restrict__ W, float* __restrict__ Wt) {
    int t = blockIdx.x * blockDim.x + threadIdx.x;
    constexpr int total = CND * 2 * CG * CK * 9; // 36864
    if (t >= total) return;
    int j = t % 9; int r = t / 9;
    int k = r % CK; r /= CK;
    int g = r % CG; int pair = r / CG;
    Wt[(pair * CG + g) * 72 + j * 8 + k] =
        W[((pair * (CG * CK)) + g * CK + k) * 9 + j];
}

// ---------------------------------------------------------------------------
// Per-block worker: one (b, pair=di*2+diff, g). Templated on DI so the
// dilation is compile-time: aligned float4 LDS tap loads for d%4==0, and
// sliding-window loads for d=1,2.
// ---------------------------------------------------------------------------
template <int DI>
__device__ __forceinline__ void run_block(const float* __restrict__ X,
                                          const float* __restrict__ Wt,
                                          const int* __restrict__ I,
                                          float* __restrict__ out,
                                          int b, int diffi, int g,
                                          float* inp, float* hist)
{
    constexpr int D = 1 << DI;
    const int pair = DI * 2 + diffi;
    const int tid  = threadIdx.x;
    const float* __restrict__ Xb = X + (size_t)b * (CC * CL);
    const int* __restrict__ Ig   = I + (pair * CG + g) * CNCP;
    const int c0 = Ig[0], c1 = Ig[1], c2 = Ig[2],
              c3 = Ig[3], c4 = Ig[4], c5 = Ig[5];

    // Zero halos (taps read them unconditionally) + histogram bins.
    for (int i = tid; i < HALO; i += 256) inp[i] = 0.f;
    for (int i = HALO + CL + tid; i < BUF; i += 256) inp[i] = 0.f;
    if (tid < 16) hist[tid] = 0.f;

    // Build summed row S[l] = sum of the 6 gathered channels (float4 chunks).
    #pragma unroll
    for (int cc = 0; cc < 2; ++cc) {
        const int pos = (tid + cc * 256) * 4;
        const float4 a0 = *(const float4*)(Xb + c0 * CL + pos);
        const float4 a1 = *(const float4*)(Xb + c1 * CL + pos);
        const float4 a2 = *(const float4*)(Xb + c2 * CL + pos);
        const float4 a3 = *(const float4*)(Xb + c3 * CL + pos);
        const float4 a4 = *(const float4*)(Xb + c4 * CL + pos);
        const float4 a5 = *(const float4*)(Xb + c5 * CL + pos);
        float4 s;
        s.x = ((a0.x + a1.x) + (a2.x + a3.x)) + (a4.x + a5.x);
        s.y = ((a0.y + a1.y) + (a2.y + a3.y)) + (a4.y + a5.y);
        s.z = ((a0.z + a1.z) + (a2.z + a3.z)) + (a4.z + a5.z);
        s.w = ((a0.w + a1.w) + (a2.w + a3.w)) + (a4.w + a5.w);
        *(float4*)&inp[HALO + pos] = s;
    }
    __syncthreads();

    // diff pair: in-place D[l] = S[l+1]-S[l] (diff of sum == sum of diffs).
    if (diffi) {
        const int l = tid * 8;
        float a[9];
        #pragma unroll
        for (int i = 0; i < 9; ++i) a[i] = inp[HALO + l + i]; // l+8<=2048 -> halo 0
        __syncthreads();
        #pragma unroll
        for (int i = 0; i < 8; ++i) inp[HALO + l + i] = a[i + 1] - a[i];
        if (tid == 255) inp[HALO + 2047] = 0.f; // position 2047 invalid (Lout=2047)
        __syncthreads();
    }

    const int Lout = CL - diffi;
    const float* __restrict__ Wg = Wt + (pair * CG + g) * 72; // [j*8+k], uniform

    #pragma unroll
    for (int pass = 0; pass < 2; ++pass) {
        const int l0 = pass * 1024 + tid * 4; // 4 consecutive positions / thread
        float zf[8][4];
        #pragma unroll
        for (int k = 0; k < 8; ++k)
            #pragma unroll
            for (int p = 0; p < 4; ++p) zf[k][p] = 0.f;

        if constexpr (D <= 2) {
            // sliding window: taps for p,j = win[p + j*D], win base at l0-4D
            constexpr int WN = (D == 1) ? 12 : 20;
            float w[WN];
            const float* base = &inp[HALO + l0 - 4 * D];
            #pragma unroll
            for (int i = 0; i < WN / 4; ++i) {
                const float4 t = *(const float4*)(base + i * 4);
                w[4 * i + 0] = t.x; w[4 * i + 1] = t.y;
                w[4 * i + 2] = t.z; w[4 * i + 3] = t.w;
            }
            #pragma unroll
            for (int j = 0; j < 9; ++j) {
                #pragma unroll
                for (int k = 0; k < 8; ++k) {
                    const float wk = Wg[j * 8 + k];
                    #pragma unroll
                    for (int p = 0; p < 4; ++p)
                        zf[k][p] = fmaf(wk, w[p + j * D], zf[k][p]);
                }
            }
        } else {
            #pragma unroll
            for (int j = 0; j < 9; ++j) {
                const float4 t = *(const float4*)&inp[HALO + l0 + (j - 4) * D];
                const float tv[4] = {t.x, t.y, t.z, t.w};
                #pragma unroll
                for (int k = 0; k < 8; ++k) {
                    const float wk = Wg[j * 8 + k];
                    #pragma unroll
                    for (int p = 0; p < 4; ++p)
                        zf[k][p] = fmaf(wk, tv[p], zf[k][p]);
                }
            }
        }

        // per-position 8-way max/argmax/argmin + LDS histogram
        #pragma unroll
        for (int p = 0; p < 4; ++p) {
            float mx = zf[0][p]; int mi = 0;
            float mn = zf[0][p]; int ni = 0;
            #pragma unroll
            for (int k = 1; k < 8; ++k) {
                const float v = zf[k][p];
                if (v > mx) { mx = v; mi = k; }
                if (v < mn) { mn = v; ni = k; }
            }
            if (l0 + p < Lout) {
                unsafeAtomicAdd(&hist[mi], mx);
                unsafeAtomicAdd(&hist[8 + ni], 1.0f);
            }
        }
    }
    __syncthreads();

    // Zs order: for di, for diff: [count_max, count_min]; col = (e*32+g)*8+k
    if (tid < 16) {
        const int which = tid >> 3, k = tid & 7;
        out[(size_t)b * 8192 + ((pair * 2 + which) * CG + g) * CK + k] = hist[tid];
    }
}

__global__ void __launch_bounds__(256)
hydra_main(const float* __restrict__ X, const float* __restrict__ Wt,
           const int* __restrict__ I, float* __restrict__ out)
{
    __shared__ float inp[BUF];
    __shared__ float hist[16];
    const int blk   = blockIdx.x;
    const int b     = blk >> 9;         // 512 blocks per batch item
    const int pair  = (blk >> 5) & 15;  // di*2 + diff
    const int g     = blk & 31;
    const int diffi = pair & 1;
    switch (pair >> 1) {
        case 0: run_block<0>(X, Wt, I, out, b, diffi, g, inp, hist); break;
        case 1: run_block<1>(X, Wt, I, out, b, diffi, g, inp, hist); break;
        case 2: run_block<2>(X, Wt, I, out, b, diffi, g, inp, hist); break;
        case 3: run_block<3>(X, Wt, I, out, b, diffi, g, inp, hist); break;
        case 4: run_block<4>(X, Wt, I, out, b, diffi, g, inp, hist); break;
        case 5: run_block<5>(X, Wt, I, out, b, diffi, g, inp, hist); break;
        case 6: run_block<6>(X, Wt, I, out, b, diffi, g, inp, hist); break;
        case 7: run_block<7>(X, Wt, I, out, b, diffi, g, inp, hist); break;
    }
}

extern "C" void kernel_launch(void* const* d_in, const int* in_sizes, int n_in,
                              void* d_out, int out_size, void* d_ws, size_t ws_size,
                              hipStream_t stream)
{
    const float* X = (const float*)d_in[0];
    const float* W = (const float*)d_in[1];
    const int*   I = (const int*)d_in[2];
    float* out = (float*)d_out;
    float* Wt  = (float*)d_ws; // 36864 floats = 144 KiB scratch

    transposeW<<<dim3((36864 + 255) / 256), dim3(256), 0, stream>>>(W, Wt);

    const int nblocks = CB * CND * 2 * CG; // 65536
    hydra_main<<<dim3(nblocks), dim3(256), 0, stream>>>(X, Wt, I, out);
}